// Round 11
// baseline (58.919 us; speedup 1.0000x reference)
//
#include <hip/hip_runtime.h>
#include <math.h>
#include <stdint.h>

#define D_MODEL 128
#define EDGE_DIM 9
#define HIDDEN 256
#define BATCH 2
#define NN 512

#define TI 4     // i-tile in kernel 2
#define TJ 32    // j-tile in kernel 2

typedef _Float16 h2v    __attribute__((ext_vector_type(2)));
typedef __fp16   fp16x2 __attribute__((ext_vector_type(2)));
typedef _Float16 f16x8  __attribute__((ext_vector_type(8)));
typedef float    f32x4  __attribute__((ext_vector_type(4)));

struct H8 { h2v v[4]; };   // 16B = one MFMA A/B fragment

__device__ __forceinline__ uint32_t h2u(h2v v) { return __builtin_bit_cast(uint32_t, v); }
__device__ __forceinline__ h2v u2h(uint32_t u) { return __builtin_bit_cast(h2v, u); }
__device__ __forceinline__ h2v pkrtz(float a, float b) {
    return __builtin_bit_cast(h2v, __builtin_amdgcn_cvt_pkrtz(a, b));
}
__device__ __forceinline__ h2v relu2(h2v v) {
    h2v z = {(_Float16)0.0f, (_Float16)0.0f};
    return __builtin_elementwise_max(v, z);
}
__device__ __forceinline__ float fdot2(h2v a, h2v b, float c) {
    return __builtin_amdgcn_fdot2(__builtin_bit_cast(fp16x2, a),
                                  __builtin_bit_cast(fp16x2, b), c, false);
}
__device__ __forceinline__ float sigmoidf_(float x) { return 1.f / (1.f + expf(-x)); }

// ---------------------------------------------------------------------------
// Kernel 1 (MFMA): C = z @ W for one of {Wo1, We_i, We_j} per block.y.
// (Unchanged from round 7.)
// ---------------------------------------------------------------------------
__global__ __launch_bounds__(512) void node_mfma_kernel(
    const float* __restrict__ z,      // (B*N, 128)
    const float* __restrict__ Wo1,    // (128,256)
    const float* __restrict__ bo1,    // (256)
    const float* __restrict__ Wo2,    // (256,1)
    const float* __restrict__ bo2,    // (1)
    const float* __restrict__ We_i,   // (128,256)
    const float* __restrict__ We_j,   // (128,256)
    const float* __restrict__ be1,    // (256)
    float* __restrict__ organ_out,    // (B*N)
    uint32_t* __restrict__ pi_h,      // (B*N,128) half2, includes +be1
    uint32_t* __restrict__ pj_h)      // (B*N,128) half2
{
    __shared__ uint32_t Wlds[256][68];     // ~69.6 KiB, f16-pair, [h][d2^swz]
    __shared__ float org_part[32][4];

    const int t    = threadIdx.x;
    const int lane = t & 63;
    const int wave = t >> 6;
    const int rb   = blockIdx.x;           // row-block: rows 32*rb..32*rb+31
    const int m    = blockIdx.y;           // 0 = Wo1/organ, 1 = We_i/pi, 2 = We_j/pj

    const float* __restrict__ W = (m == 0) ? Wo1 : (m == 1) ? We_i : We_j;

    // ---- stage W -> LDS f16, transposed, swizzled ----
    for (int idx = t; idx < 64 * 256; idx += 512) {
        const int d2 = idx >> 8;           // 0..63 (d-pair)
        const int h  = idx & 255;          // coalesced over h
        const float wlo = W[(2 * d2) * 256 + h];
        const float whi = W[(2 * d2 + 1) * 256 + h];
        Wlds[h][d2 ^ ((h & 7) << 3)] = h2u(pkrtz(wlo, whi));
    }

    // ---- A-frags straight from global ----
    const int rt = wave & 1;               // row-tile
    const int cg = wave >> 1;              // col-group (4 tiles of 16)
    const int kg = lane >> 4;              // k-subgroup
    const int row = rb * 32 + rt * 16 + (lane & 15);

    f16x8 A[4];
#pragma unroll
    for (int kt = 0; kt < 4; ++kt) {
        const float4 za = *(const float4*)&z[(size_t)row * 128 + kt * 32 + kg * 8];
        const float4 zb = *(const float4*)&z[(size_t)row * 128 + kt * 32 + kg * 8 + 4];
        H8 a;
        a.v[0] = pkrtz(za.x, za.y); a.v[1] = pkrtz(za.z, za.w);
        a.v[2] = pkrtz(zb.x, zb.y); a.v[3] = pkrtz(zb.z, zb.w);
        A[kt] = __builtin_bit_cast(f16x8, a);
    }

    __syncthreads();

    // ---- MFMA main: 4 col-tiles x 4 k-tiles ----
    f32x4 C[4];
#pragma unroll
    for (int ct = 0; ct < 4; ++ct) {
        const int col = (cg * 4 + ct) * 16 + (lane & 15);
        C[ct] = (f32x4){0.f, 0.f, 0.f, 0.f};
#pragma unroll
        for (int kt = 0; kt < 4; ++kt) {
            const int d2b = (kt * 16 + kg * 4) ^ ((col & 7) << 3);
            const uint4 w = *(const uint4*)&Wlds[col][d2b];
            H8 b;
            b.v[0] = u2h(w.x); b.v[1] = u2h(w.y);
            b.v[2] = u2h(w.z); b.v[3] = u2h(w.w);
            C[ct] = __builtin_amdgcn_mfma_f32_16x16x32_f16(
                        A[kt], __builtin_bit_cast(f16x8, b), C[ct], 0, 0, 0);
        }
    }

    // ---- epilogues ----
    if (m == 0) {
        float s0 = 0.f, s1 = 0.f, s2 = 0.f, s3 = 0.f;
#pragma unroll
        for (int ct = 0; ct < 4; ++ct) {
            const int col = (cg * 4 + ct) * 16 + (lane & 15);
            const float b1 = bo1[col];
            const float w2 = Wo2[col];
            s0 = fmaf(fmaxf(C[ct].x + b1, 0.f), w2, s0);
            s1 = fmaf(fmaxf(C[ct].y + b1, 0.f), w2, s1);
            s2 = fmaf(fmaxf(C[ct].z + b1, 0.f), w2, s2);
            s3 = fmaf(fmaxf(C[ct].w + b1, 0.f), w2, s3);
        }
#pragma unroll
        for (int off = 1; off <= 8; off <<= 1) {
            s0 += __shfl_xor(s0, off, 64);
            s1 += __shfl_xor(s1, off, 64);
            s2 += __shfl_xor(s2, off, 64);
            s3 += __shfl_xor(s3, off, 64);
        }
        if ((lane & 15) == 0) {
            const int rbase = rt * 16 + kg * 4;
            org_part[rbase + 0][cg] = s0;
            org_part[rbase + 1][cg] = s1;
            org_part[rbase + 2][cg] = s2;
            org_part[rbase + 3][cg] = s3;
        }
        __syncthreads();
        if (t < 32) {
            const float s = org_part[t][0] + org_part[t][1]
                          + org_part[t][2] + org_part[t][3] + bo2[0];
            organ_out[rb * 32 + t] = sigmoidf_(s);
        }
    } else {
        uint32_t* __restrict__ dst = (m == 1) ? pi_h : pj_h;
        const bool addb = (m == 1);
#pragma unroll
        for (int ct = 0; ct < 4; ++ct) {
            const int col = (cg * 4 + ct) * 16 + (lane & 15);
            const float bv = addb ? be1[col] : 0.f;
            float v0 = C[ct].x + bv, v1 = C[ct].y + bv;
            float v2 = C[ct].z + bv, v3 = C[ct].w + bv;
            const float p0 = __shfl_xor(v0, 1, 64);
            const float p1 = __shfl_xor(v1, 1, 64);
            const float p2 = __shfl_xor(v2, 1, 64);
            const float p3 = __shfl_xor(v3, 1, 64);
            if (!(lane & 1)) {                 // even col: pack (col, col+1)
                const int hp = col >> 1;
                const size_t gr = (size_t)(rb * 32 + rt * 16 + kg * 4);
                dst[(gr + 0) * 128 + hp] = h2u(pkrtz(v0, p0));
                dst[(gr + 1) * 128 + hp] = h2u(pkrtz(v1, p1));
                dst[(gr + 2) * 128 + hp] = h2u(pkrtz(v2, p2));
                dst[(gr + 3) * 128 + hp] = h2u(pkrtz(v3, p3));
            }
        }
    }
}

// ---------------------------------------------------------------------------
// Kernel 2: fused edge head, NO mask-skip (round-7 unconditional body —
// mask-skip proven net-negative in rounds 8-10: the per-(q,ii) branch broke
// cross-ii LDS pipelining), PLUS the truncated reduce from round 10:
// 3 select+exchange levels only (serial DS chain 6 -> 3 per q); each lane
// parks its subgroup partial in part_s[wave][q][o][sub]; fully parallel
// epilogue (each of 256 threads sums 8 floats for one output).
// ---------------------------------------------------------------------------
__global__ __launch_bounds__(256, 8) void edge_kernel(
    const float* __restrict__ E,      // (N,N,9)
    const int*   __restrict__ mask,   // (N,N)
    const float* __restrict__ We_e,   // (9,256)
    const float* __restrict__ We2,    // (256,1)
    const float* __restrict__ be2,    // (1)
    const uint32_t* __restrict__ pi_h,  // (B*N,128) half2
    const uint32_t* __restrict__ pj_h,  // (B*N,128) half2
    float* __restrict__ edge_out)     // (B,N,N)
{
    __shared__ __align__(16) uint32_t E_s[TI][TJ][12];  // dup'd h2v, 6 KiB
    __shared__ __align__(16) float part_s[4][8][8][8];  // [wave][q][o][sub], 8 KiB
    __shared__ uint32_t mask4_s[TJ];                    // 4 mask bits per jl

    const int t    = threadIdx.x;
    const int lane = t & 63;
    const int wave = t >> 6;           // 0..3
    const int bi   = blockIdx.x;
    const int i0   = (bi >> 4) * TI;   // 128 i-blocks
    const int j0   = (bi & 15) * TJ;   // 16 j-blocks

#pragma unroll
    for (int ii = 0; ii < TI; ++ii) {
        const float* src = &E[((size_t)(i0 + ii) * NN + j0) * EDGE_DIM];
        for (int idx = t; idx < TJ * EDGE_DIM; idx += 256) {
            const int jl = idx / 9;
            const int d  = idx - jl * 9;
            const float e = src[idx];
            E_s[ii][jl][d] = h2u(pkrtz(e, e));
        }
    }
    // ---- stage mask bits for the epilogue multiply ----
    if (t < TJ) {
        uint32_t m = 0;
#pragma unroll
        for (int ii = 0; ii < TI; ++ii)
            m |= (mask[(size_t)(i0 + ii) * NN + j0 + t] != 0 ? 1u : 0u) << ii;
        mask4_s[t] = m;
    }

    h2v wee[EDGE_DIM][2];
    const float4* We_e4 = (const float4*)We_e;
#pragma unroll
    for (int d = 0; d < EDGE_DIM; ++d) {
        const float4 w = We_e4[d * 64 + lane];
        wee[d][0] = pkrtz(w.x, w.y);
        wee[d][1] = pkrtz(w.z, w.w);
    }
    h2v w2[2];
    {
        const float4 w = ((const float4*)We2)[lane];
        w2[0] = pkrtz(w.x, w.y);
        w2[1] = pkrtz(w.z, w.w);
    }

    h2v pir[BATCH][TI][2];
#pragma unroll
    for (int b = 0; b < BATCH; ++b)
#pragma unroll
        for (int ii = 0; ii < TI; ++ii) {
            const uint2 u = ((const uint2*)&pi_h[(size_t)(b * NN + i0 + ii) * 128])[lane];
            pir[b][ii][0] = u2h(u.x);
            pir[b][ii][1] = u2h(u.y);
        }

    __syncthreads();

    uint2 pjp[BATCH];
    {
        const int j = j0 + wave * 8;
        pjp[0] = ((const uint2*)&pj_h[(size_t)(0 * NN + j) * 128])[lane];
        pjp[1] = ((const uint2*)&pj_h[(size_t)(1 * NN + j) * 128])[lane];
    }

#pragma unroll
    for (int q = 0; q < 8; ++q) {
        const int jl = wave * 8 + q;

        h2v pjr[BATCH][2];
        pjr[0][0] = u2h(pjp[0].x); pjr[0][1] = u2h(pjp[0].y);
        pjr[1][0] = u2h(pjp[1].x); pjr[1][1] = u2h(pjp[1].y);

        if (q < 7) {
            const int j = j0 + jl + 1;
            pjp[0] = ((const uint2*)&pj_h[(size_t)(0 * NN + j) * 128])[lane];
            pjp[1] = ((const uint2*)&pj_h[(size_t)(1 * NN + j) * 128])[lane];
        }

        float vals[8];
#pragma unroll
        for (int ii = 0; ii < TI; ++ii) {
            const uint32_t* erow = &E_s[ii][jl][0];
            const uint4 ua = *(const uint4*)(erow);
            const uint4 ub = *(const uint4*)(erow + 4);
            const uint32_t uc = erow[8];

            h2v pe0, pe1;
            {
                const h2v e0 = u2h(ua.x), e1 = u2h(ua.y), e2 = u2h(ua.z), e3 = u2h(ua.w);
                const h2v e4 = u2h(ub.x), e5 = u2h(ub.y), e6 = u2h(ub.z), e7 = u2h(ub.w);
                const h2v e8 = u2h(uc);
                pe0 = e0 * wee[0][0];            pe1 = e0 * wee[0][1];
                pe0 = pe0 + e1 * wee[1][0];      pe1 = pe1 + e1 * wee[1][1];
                pe0 = pe0 + e2 * wee[2][0];      pe1 = pe1 + e2 * wee[2][1];
                pe0 = pe0 + e3 * wee[3][0];      pe1 = pe1 + e3 * wee[3][1];
                pe0 = pe0 + e4 * wee[4][0];      pe1 = pe1 + e4 * wee[4][1];
                pe0 = pe0 + e5 * wee[5][0];      pe1 = pe1 + e5 * wee[5][1];
                pe0 = pe0 + e6 * wee[6][0];      pe1 = pe1 + e6 * wee[6][1];
                pe0 = pe0 + e7 * wee[7][0];      pe1 = pe1 + e7 * wee[7][1];
                pe0 = pe0 + e8 * wee[8][0];      pe1 = pe1 + e8 * wee[8][1];
            }

#pragma unroll
            for (int b = 0; b < BATCH; ++b) {
                h2v v0 = relu2(pir[b][ii][0] + pjr[b][0] + pe0);
                h2v v1 = relu2(pir[b][ii][1] + pjr[b][1] + pe1);
                vals[2 * ii + b] = fdot2(v1, w2[1], fdot2(v0, w2[0], 0.f));
            }
        }

        // ---- 3-level select+exchange: lane ends with partial of output
        // o = lane&7 over subgroup sub = lane>>3 ----
        float a0, a1, a2, a3;
        {
            const bool b0 = lane & 1;
            float k0 = b0 ? vals[1] : vals[0], s0 = b0 ? vals[0] : vals[1];
            float k1 = b0 ? vals[3] : vals[2], s1 = b0 ? vals[2] : vals[3];
            float k2 = b0 ? vals[5] : vals[4], s2 = b0 ? vals[4] : vals[5];
            float k3 = b0 ? vals[7] : vals[6], s3 = b0 ? vals[6] : vals[7];
            a0 = k0 + __shfl_xor(s0, 1, 64);
            a1 = k1 + __shfl_xor(s1, 1, 64);
            a2 = k2 + __shfl_xor(s2, 1, 64);
            a3 = k3 + __shfl_xor(s3, 1, 64);
        }
        {
            const bool b1 = (lane >> 1) & 1;
            float k0 = b1 ? a1 : a0, s0 = b1 ? a0 : a1;
            float k1 = b1 ? a3 : a2, s1 = b1 ? a2 : a3;
            a0 = k0 + __shfl_xor(s0, 2, 64);
            a1 = k1 + __shfl_xor(s1, 2, 64);
        }
        {
            const bool b2 = (lane >> 2) & 1;
            float k = b2 ? a1 : a0, s = b2 ? a0 : a1;
            a0 = k + __shfl_xor(s, 4, 64);
        }

        // park subgroup partial; all 64 lanes write distinct slots
        part_s[wave][q][lane & 7][lane >> 3] = a0;
    }
    __syncthreads();

    // ---- parallel epilogue: thread t -> (wave w, q, output o) ----
    {
        const int w  = t >> 6;
        const int qq = (t >> 3) & 7;
        const int o  = t & 7;
        const int b  = o & 1;
        const int ii = o >> 1;
        const int jl = w * 8 + qq;
        const int i = i0 + ii, j = j0 + jl;

        const float4 pa = *(const float4*)&part_s[w][qq][o][0];
        const float4 pb = *(const float4*)&part_s[w][qq][o][4];
        const float s = ((pa.x + pa.y) + (pa.z + pa.w))
                      + ((pb.x + pb.y) + (pb.z + pb.w)) + be2[0];
        const float mv = (float)((mask4_s[jl] >> ii) & 1u);
        edge_out[((size_t)b * NN + i) * NN + j] = sigmoidf_(s) * mv;
    }
}

extern "C" void kernel_launch(void* const* d_in, const int* in_sizes, int n_in,
                              void* d_out, int out_size, void* d_ws, size_t ws_size,
                              hipStream_t stream) {
    const float* z    = (const float*)d_in[0];   // (B,N,128)
    const float* E    = (const float*)d_in[1];   // (N,N,9)
    const int*   mask = (const int*)  d_in[2];   // (N,N)
    const float* Wo1  = (const float*)d_in[3];
    const float* bo1  = (const float*)d_in[4];
    const float* Wo2  = (const float*)d_in[5];
    const float* bo2  = (const float*)d_in[6];
    const float* We_i = (const float*)d_in[7];
    const float* We_j = (const float*)d_in[8];
    const float* We_e = (const float*)d_in[9];
    const float* be1  = (const float*)d_in[10];
    const float* We2  = (const float*)d_in[11];
    const float* be2  = (const float*)d_in[12];

    float* out_organ = (float*)d_out;                 // (B,N) = 1024
    float* out_edge  = out_organ + BATCH * NN;        // (B,N,N)

    uint32_t* pi_h = (uint32_t*)d_ws;                        // (B*N,128) half2
    uint32_t* pj_h = pi_h + (size_t)BATCH * NN * (HIDDEN/2); // (B*N,128) half2

    hipLaunchKernelGGL(node_mfma_kernel,
                       dim3(32, 3), dim3(512), 0, stream,
                       z, Wo1, bo1, Wo2, bo2, We_i, We_j, be1,
                       out_organ, pi_h, pj_h);

    hipLaunchKernelGGL(edge_kernel,
                       dim3((NN / TI) * (NN / TJ)), dim3(256), 0, stream,
                       E, mask, We_e, We2, be2, pi_h, pj_h, out_edge);
}

// Round 12
// 42.776 us; speedup vs baseline: 1.3774x; 1.3774x over previous
//
#include <hip/hip_runtime.h>
#include <math.h>
#include <stdint.h>

#define D_MODEL 128
#define EDGE_DIM 9
#define HIDDEN 256
#define BATCH 2
#define NN 512

typedef _Float16 h2v    __attribute__((ext_vector_type(2)));
typedef __fp16   fp16x2 __attribute__((ext_vector_type(2)));
typedef _Float16 f16x8  __attribute__((ext_vector_type(8)));
typedef float    f32x4  __attribute__((ext_vector_type(4)));

struct H8 { h2v v[4]; };   // 16B = one MFMA A/B fragment

__device__ __forceinline__ uint32_t h2u(h2v v) { return __builtin_bit_cast(uint32_t, v); }
__device__ __forceinline__ h2v u2h(uint32_t u) { return __builtin_bit_cast(h2v, u); }
__device__ __forceinline__ h2v pkrtz(float a, float b) {
    return __builtin_bit_cast(h2v, __builtin_amdgcn_cvt_pkrtz(a, b));
}
__device__ __forceinline__ h2v relu2(h2v v) {
    h2v z = {(_Float16)0.0f, (_Float16)0.0f};
    return __builtin_elementwise_max(v, z);
}
__device__ __forceinline__ float fdot2(h2v a, h2v b, float c) {
    return __builtin_amdgcn_fdot2(__builtin_bit_cast(fp16x2, a),
                                  __builtin_bit_cast(fp16x2, b), c, false);
}
__device__ __forceinline__ float sigmoidf_(float x) { return 1.f / (1.f + expf(-x)); }
// uint4 element by unroll-constant index (folds to .x/.y/.z/.w)
__device__ __forceinline__ uint32_t el(const uint4& u, int k) {
    switch (k) { case 0: return u.x; case 1: return u.y; case 2: return u.z; default: return u.w; }
}

// ---------------------------------------------------------------------------
// Kernel 1 (MFMA): C = z @ W for one of {Wo1, We_i, We_j} per block.y.
// Same as round 7 except m==2 (pj) now stores TRANSPOSED: pj_T[hp][row]
// (row = b*N+n), so the edge kernel can read pj coalesced per-h2 with
// lane = j. Scattered 4B writes here are fire-and-forget.
// ---------------------------------------------------------------------------
__global__ __launch_bounds__(512) void node_mfma_kernel(
    const float* __restrict__ z,      // (B*N, 128)
    const float* __restrict__ Wo1,    // (128,256)
    const float* __restrict__ bo1,    // (256)
    const float* __restrict__ Wo2,    // (256,1)
    const float* __restrict__ bo2,    // (1)
    const float* __restrict__ We_i,   // (128,256)
    const float* __restrict__ We_j,   // (128,256)
    const float* __restrict__ be1,    // (256)
    float* __restrict__ organ_out,    // (B*N)
    uint32_t* __restrict__ pi_h,      // (B*N,128) half2 rows, includes +be1
    uint32_t* __restrict__ pj_T)      // (128,B*N) half2 TRANSPOSED
{
    __shared__ uint32_t Wlds[256][68];     // ~69.6 KiB, f16-pair, [h][d2^swz]
    __shared__ float org_part[32][4];

    const int t    = threadIdx.x;
    const int lane = t & 63;
    const int wave = t >> 6;
    const int rb   = blockIdx.x;           // row-block: rows 32*rb..32*rb+31
    const int m    = blockIdx.y;           // 0 = Wo1/organ, 1 = We_i/pi, 2 = We_j/pj

    const float* __restrict__ W = (m == 0) ? Wo1 : (m == 1) ? We_i : We_j;

    // ---- stage W -> LDS f16, transposed, swizzled ----
    for (int idx = t; idx < 64 * 256; idx += 512) {
        const int d2 = idx >> 8;           // 0..63 (d-pair)
        const int h  = idx & 255;          // coalesced over h
        const float wlo = W[(2 * d2) * 256 + h];
        const float whi = W[(2 * d2 + 1) * 256 + h];
        Wlds[h][d2 ^ ((h & 7) << 3)] = h2u(pkrtz(wlo, whi));
    }

    // ---- A-frags straight from global ----
    const int rt = wave & 1;               // row-tile
    const int cg = wave >> 1;              // col-group (4 tiles of 16)
    const int kg = lane >> 4;              // k-subgroup
    const int row = rb * 32 + rt * 16 + (lane & 15);

    f16x8 A[4];
#pragma unroll
    for (int kt = 0; kt < 4; ++kt) {
        const float4 za = *(const float4*)&z[(size_t)row * 128 + kt * 32 + kg * 8];
        const float4 zb = *(const float4*)&z[(size_t)row * 128 + kt * 32 + kg * 8 + 4];
        H8 a;
        a.v[0] = pkrtz(za.x, za.y); a.v[1] = pkrtz(za.z, za.w);
        a.v[2] = pkrtz(zb.x, zb.y); a.v[3] = pkrtz(zb.z, zb.w);
        A[kt] = __builtin_bit_cast(f16x8, a);
    }

    __syncthreads();

    // ---- MFMA main: 4 col-tiles x 4 k-tiles ----
    f32x4 C[4];
#pragma unroll
    for (int ct = 0; ct < 4; ++ct) {
        const int col = (cg * 4 + ct) * 16 + (lane & 15);
        C[ct] = (f32x4){0.f, 0.f, 0.f, 0.f};
#pragma unroll
        for (int kt = 0; kt < 4; ++kt) {
            const int d2b = (kt * 16 + kg * 4) ^ ((col & 7) << 3);
            const uint4 w = *(const uint4*)&Wlds[col][d2b];
            H8 b;
            b.v[0] = u2h(w.x); b.v[1] = u2h(w.y);
            b.v[2] = u2h(w.z); b.v[3] = u2h(w.w);
            C[ct] = __builtin_amdgcn_mfma_f32_16x16x32_f16(
                        A[kt], __builtin_bit_cast(f16x8, b), C[ct], 0, 0, 0);
        }
    }

    // ---- epilogues ----
    if (m == 0) {
        float s0 = 0.f, s1 = 0.f, s2 = 0.f, s3 = 0.f;
#pragma unroll
        for (int ct = 0; ct < 4; ++ct) {
            const int col = (cg * 4 + ct) * 16 + (lane & 15);
            const float b1 = bo1[col];
            const float w2 = Wo2[col];
            s0 = fmaf(fmaxf(C[ct].x + b1, 0.f), w2, s0);
            s1 = fmaf(fmaxf(C[ct].y + b1, 0.f), w2, s1);
            s2 = fmaf(fmaxf(C[ct].z + b1, 0.f), w2, s2);
            s3 = fmaf(fmaxf(C[ct].w + b1, 0.f), w2, s3);
        }
#pragma unroll
        for (int off = 1; off <= 8; off <<= 1) {
            s0 += __shfl_xor(s0, off, 64);
            s1 += __shfl_xor(s1, off, 64);
            s2 += __shfl_xor(s2, off, 64);
            s3 += __shfl_xor(s3, off, 64);
        }
        if ((lane & 15) == 0) {
            const int rbase = rt * 16 + kg * 4;
            org_part[rbase + 0][cg] = s0;
            org_part[rbase + 1][cg] = s1;
            org_part[rbase + 2][cg] = s2;
            org_part[rbase + 3][cg] = s3;
        }
        __syncthreads();
        if (t < 32) {
            const float s = org_part[t][0] + org_part[t][1]
                          + org_part[t][2] + org_part[t][3] + bo2[0];
            organ_out[rb * 32 + t] = sigmoidf_(s);
        }
    } else if (m == 1) {
        // pi: row-major [row][hp], +be1
#pragma unroll
        for (int ct = 0; ct < 4; ++ct) {
            const int col = (cg * 4 + ct) * 16 + (lane & 15);
            const float bv = be1[col];
            float v0 = C[ct].x + bv, v1 = C[ct].y + bv;
            float v2 = C[ct].z + bv, v3 = C[ct].w + bv;
            const float p0 = __shfl_xor(v0, 1, 64);
            const float p1 = __shfl_xor(v1, 1, 64);
            const float p2 = __shfl_xor(v2, 1, 64);
            const float p3 = __shfl_xor(v3, 1, 64);
            if (!(lane & 1)) {
                const int hp = col >> 1;
                const size_t gr = (size_t)(rb * 32 + rt * 16 + kg * 4);
                pi_h[(gr + 0) * 128 + hp] = h2u(pkrtz(v0, p0));
                pi_h[(gr + 1) * 128 + hp] = h2u(pkrtz(v1, p1));
                pi_h[(gr + 2) * 128 + hp] = h2u(pkrtz(v2, p2));
                pi_h[(gr + 3) * 128 + hp] = h2u(pkrtz(v3, p3));
            }
        }
    } else {
        // pj: TRANSPOSED [hp][row]
#pragma unroll
        for (int ct = 0; ct < 4; ++ct) {
            const int col = (cg * 4 + ct) * 16 + (lane & 15);
            float v0 = C[ct].x, v1 = C[ct].y, v2 = C[ct].z, v3 = C[ct].w;
            const float p0 = __shfl_xor(v0, 1, 64);
            const float p1 = __shfl_xor(v1, 1, 64);
            const float p2 = __shfl_xor(v2, 1, 64);
            const float p3 = __shfl_xor(v3, 1, 64);
            if (!(lane & 1)) {
                const int hp = col >> 1;
                const size_t gr = (size_t)(rb * 32 + rt * 16 + kg * 4);
                pj_T[(size_t)hp * (BATCH * NN) + gr + 0] = h2u(pkrtz(v0, p0));
                pj_T[(size_t)hp * (BATCH * NN) + gr + 1] = h2u(pkrtz(v1, p1));
                pj_T[(size_t)hp * (BATCH * NN) + gr + 2] = h2u(pkrtz(v2, p2));
                pj_T[(size_t)hp * (BATCH * NN) + gr + 3] = h2u(pkrtz(v3, p3));
            }
        }
    }
}

// ---------------------------------------------------------------------------
// Kernel 2: fused edge head, REDUCTION-FREE (lane = j).
// grid 512 x 256 thr (4 waves). Block tile: 8 i x 64 j; wave w owns i-pair
// (i0+2w, i0+2w+1); lane owns j = j0+lane for ALL 256 h (serial h-loop,
// 4-h2 chunks). acc[i][b] is a per-lane f32 -> NO cross-lane reduce, no
// shfl, no main-loop barriers. Operands: wee/we2/pi broadcast from LDS
// (b128); pj read coalesced from pj_T (4B/lane per h2); E in 18 h2v regs.
// ---------------------------------------------------------------------------
__global__ __launch_bounds__(256, 4) void edge_kernel(
    const float* __restrict__ E,      // (N,N,9)
    const int*   __restrict__ mask,   // (N,N)
    const float* __restrict__ We_e,   // (9,256)
    const float* __restrict__ We2,    // (256,1)
    const float* __restrict__ be2,    // (1)
    const uint32_t* __restrict__ pi_h,  // (B*N,128) half2 rows
    const uint32_t* __restrict__ pj_T,  // (128,B*N) half2 transposed
    float* __restrict__ edge_out)     // (B,N,N)
{
    __shared__ __align__(16) uint32_t E_s[8][64][12];    // dup'd h2v, 12 KiB
    __shared__ __align__(16) uint32_t wee_s[EDGE_DIM][128]; // 4.5 KiB
    __shared__ __align__(16) uint32_t we2_s[128];           // 0.5 KiB
    __shared__ __align__(16) uint32_t pi_s[BATCH][8][128];  // 8 KiB

    const int t    = threadIdx.x;
    const int lane = t & 63;
    const int w    = t >> 6;           // wave 0..3 -> i-pair
    const int bi   = blockIdx.x;
    const int i0   = (bi >> 3) * 8;    // 64 i-blocks
    const int j0   = (bi & 7) * 64;    // 8 j-blocks

    // ---- stage E tile (8 rows x 64 j x 9 d, dup'd f16 pairs) ----
#pragma unroll
    for (int ii = 0; ii < 8; ++ii) {
        const float* src = &E[((size_t)(i0 + ii) * NN + j0) * EDGE_DIM];
        for (int idx = t; idx < 64 * EDGE_DIM; idx += 256) {
            const int jl = idx / 9;
            const int d  = idx - jl * 9;
            const float e = src[idx];
            E_s[ii][jl][d] = h2u(pkrtz(e, e));
        }
    }
    // ---- stage We_e as h2v [d][h2] ----
    for (int idx = t; idx < EDGE_DIM * 128; idx += 256) {
        const int d  = idx >> 7;
        const int h2 = idx & 127;
        wee_s[d][h2] = h2u(pkrtz(We_e[d * 256 + 2 * h2], We_e[d * 256 + 2 * h2 + 1]));
    }
    // ---- stage We2 as h2v ----
    if (t < 128) we2_s[t] = h2u(pkrtz(We2[2 * t], We2[2 * t + 1]));
    // ---- stage pi rows for this block's 8 i x 2 b ----
    {
        // 16 rows x 128 uint32 = 512 uint4; 2 per thread
#pragma unroll
        for (int k = 0; k < 2; ++k) {
            const int idx = t + k * 256;          // 0..511
            const int r16 = idx >> 5;             // row 0..15
            const int c4  = idx & 31;             // uint4 col
            const int b   = r16 >> 3;
            const int il  = r16 & 7;
            const uint4 v = *(const uint4*)&pi_h[(size_t)(b * NN + i0 + il) * 128 + c4 * 4];
            *(uint4*)&pi_s[b][il][c4 * 4] = v;
        }
    }
    __syncthreads();

    // ---- per-lane E registers: 2 i x 9 d ----
    h2v e0[9], e1[9];
    {
        const uint32_t* r0 = &E_s[2 * w + 0][lane][0];
        const uint4 a0 = *(const uint4*)(r0);
        const uint4 b0 = *(const uint4*)(r0 + 4);
        e0[0]=u2h(a0.x); e0[1]=u2h(a0.y); e0[2]=u2h(a0.z); e0[3]=u2h(a0.w);
        e0[4]=u2h(b0.x); e0[5]=u2h(b0.y); e0[6]=u2h(b0.z); e0[7]=u2h(b0.w);
        e0[8]=u2h(r0[8]);
        const uint32_t* r1 = &E_s[2 * w + 1][lane][0];
        const uint4 a1 = *(const uint4*)(r1);
        const uint4 b1 = *(const uint4*)(r1 + 4);
        e1[0]=u2h(a1.x); e1[1]=u2h(a1.y); e1[2]=u2h(a1.z); e1[3]=u2h(a1.w);
        e1[4]=u2h(b1.x); e1[5]=u2h(b1.y); e1[6]=u2h(b1.z); e1[7]=u2h(b1.w);
        e1[8]=u2h(r1[8]);
    }

    float acc[2][2] = {{0.f, 0.f}, {0.f, 0.f}};   // [ii][b]

    const uint32_t* pjbase0 = pj_T + j0 + lane;            // b = 0
    const uint32_t* pjbase1 = pj_T + NN + j0 + lane;       // b = 1

    for (int hc = 0; hc < 128; hc += 4) {
        // broadcast operands (b128, wave-uniform address)
        uint4 wee4[EDGE_DIM];
#pragma unroll
        for (int d = 0; d < EDGE_DIM; ++d) wee4[d] = *(const uint4*)&wee_s[d][hc];
        const uint4 we24 = *(const uint4*)&we2_s[hc];
        uint4 pi4[2][2];   // [b][ii]
#pragma unroll
        for (int b = 0; b < 2; ++b) {
            pi4[b][0] = *(const uint4*)&pi_s[b][2 * w + 0][hc];
            pi4[b][1] = *(const uint4*)&pi_s[b][2 * w + 1][hc];
        }
        // coalesced per-lane pj
        uint32_t pjv0[4], pjv1[4];
#pragma unroll
        for (int k = 0; k < 4; ++k) {
            pjv0[k] = pjbase0[(size_t)(hc + k) * (BATCH * NN)];
            pjv1[k] = pjbase1[(size_t)(hc + k) * (BATCH * NN)];
        }

#pragma unroll
        for (int k = 0; k < 4; ++k) {
            const h2v w2k = u2h(el(we24, k));
            // ii = 0
            {
                h2v pe = e0[0] * u2h(el(wee4[0], k));
#pragma unroll
                for (int d = 1; d < EDGE_DIM; ++d) pe += e0[d] * u2h(el(wee4[d], k));
                h2v t0 = relu2(pe + u2h(pjv0[k]) + u2h(el(pi4[0][0], k)));
                acc[0][0] = fdot2(t0, w2k, acc[0][0]);
                h2v t1 = relu2(pe + u2h(pjv1[k]) + u2h(el(pi4[1][0], k)));
                acc[0][1] = fdot2(t1, w2k, acc[0][1]);
            }
            // ii = 1
            {
                h2v pe = e1[0] * u2h(el(wee4[0], k));
#pragma unroll
                for (int d = 1; d < EDGE_DIM; ++d) pe += e1[d] * u2h(el(wee4[d], k));
                h2v t0 = relu2(pe + u2h(pjv0[k]) + u2h(el(pi4[0][1], k)));
                acc[1][0] = fdot2(t0, w2k, acc[1][0]);
                h2v t1 = relu2(pe + u2h(pjv1[k]) + u2h(el(pi4[1][1], k)));
                acc[1][1] = fdot2(t1, w2k, acc[1][1]);
            }
        }
    }

    // ---- epilogue: 4 outputs per lane, coalesced stores ----
    const float b2 = be2[0];
#pragma unroll
    for (int ii = 0; ii < 2; ++ii) {
        const int i = i0 + 2 * w + ii;
        const float mv = (float)mask[(size_t)i * NN + j0 + lane];
#pragma unroll
        for (int b = 0; b < 2; ++b) {
            const float s = acc[ii][b] + b2;
            edge_out[((size_t)b * NN + i) * NN + j0 + lane] = sigmoidf_(s) * mv;
        }
    }
}

extern "C" void kernel_launch(void* const* d_in, const int* in_sizes, int n_in,
                              void* d_out, int out_size, void* d_ws, size_t ws_size,
                              hipStream_t stream) {
    const float* z    = (const float*)d_in[0];   // (B,N,128)
    const float* E    = (const float*)d_in[1];   // (N,N,9)
    const int*   mask = (const int*)  d_in[2];   // (N,N)
    const float* Wo1  = (const float*)d_in[3];
    const float* bo1  = (const float*)d_in[4];
    const float* Wo2  = (const float*)d_in[5];
    const float* bo2  = (const float*)d_in[6];
    const float* We_i = (const float*)d_in[7];
    const float* We_j = (const float*)d_in[8];
    const float* We_e = (const float*)d_in[9];
    const float* be1  = (const float*)d_in[10];
    const float* We2  = (const float*)d_in[11];
    const float* be2  = (const float*)d_in[12];

    float* out_organ = (float*)d_out;                 // (B,N) = 1024
    float* out_edge  = out_organ + BATCH * NN;        // (B,N,N)

    uint32_t* pi_h = (uint32_t*)d_ws;                        // (B*N,128) half2
    uint32_t* pj_T = pi_h + (size_t)BATCH * NN * (HIDDEN/2); // (128,B*N) half2

    hipLaunchKernelGGL(node_mfma_kernel,
                       dim3(32, 3), dim3(512), 0, stream,
                       z, Wo1, bo1, Wo2, bo2, We_i, We_j, be1,
                       out_organ, pi_h, pj_T);

    hipLaunchKernelGGL(edge_kernel,
                       dim3(64 * 8), dim3(256), 0, stream,
                       E, mask, We_e, We2, be2, pi_h, pj_T, out_edge);
}